// Round 20
// baseline (233.445 us; speedup 1.0000x reference)
//
#include <hip/hip_runtime.h>
#include <math.h>

#define N_NODES 10000
#define N_EDGES 100000
#define DIM 256
#define NCH 4
#define HIDD 8
#define OUTD 4

#define BM 128
#define NTM 79              // ceil(10000/128)
#define NBANDS 8            // bn bands; each band = 4 tiles of 128 cols
#define TPB 4               // bn tiles per band (32 total / 8 bands)
#define GEMM_BLKS (NTM * NBANDS)   // 632
#define SCAT_BLKS 391       // ceil(100000/256), appended to gemm launch

// prep kernel block ranges
#define PREP_CVT_BLKS 1250  // 10000*256/8 / 256
#define PREP_PACK_BLKS 512
#define PREP_DEG_BLKS 391   // ceil(100000/256)

#define MAXDEG 320          // Poisson(10) max deg ~40; 8x safety for LDS alpha stash

typedef _Float16 h8v __attribute__((ext_vector_type(8)));  // 8 f16 in 4 VGPRs (MFMA frag)
typedef _Float16 h2v __attribute__((ext_vector_type(2)));  // packed pair for v_dot2
typedef float f4v __attribute__((ext_vector_type(4)));     // MFMA accumulator

__device__ __forceinline__ float4 ldf4(const float* p) {
    return *reinterpret_cast<const float4*>(p);
}
__device__ __forceinline__ unsigned short f2h(float f) {   // f32 -> f16 (RNE via HW cvt)
    _Float16 h = (_Float16)f;
    return __builtin_bit_cast(unsigned short, h);
}
__device__ __forceinline__ h2v u2h2(unsigned int u) {
    return __builtin_bit_cast(h2v, u);
}
// 4-element f16 dot with f32 accumulate; v_dot2_f32_f16 if available
__device__ __forceinline__ float dot4h(uint2 a, uint2 b, float acc) {
#if __has_builtin(__builtin_amdgcn_fdot2)
    acc = __builtin_amdgcn_fdot2(u2h2(a.x), u2h2(b.x), acc, false);
    acc = __builtin_amdgcn_fdot2(u2h2(a.y), u2h2(b.y), acc, false);
#else
    h2v ax = u2h2(a.x), ay = u2h2(a.y), bx = u2h2(b.x), by = u2h2(b.y);
    acc += (float)ax.x*(float)bx.x + (float)ax.y*(float)bx.y
         + (float)ay.x*(float)by.x + (float)ay.y*(float)by.y;
#endif
    return acc;
}
// fast tanh: (e-1)/(e+1), e=exp(2x)
__device__ __forceinline__ float fast_tanh(float x) {
    float xc = fminf(fmaxf(x, -15.f), 15.f);
    float e = __expf(2.f * xc);
    return (e - 1.f) * __builtin_amdgcn_rcpf(e + 1.f);
}
__device__ __forceinline__ float fast_elu(float z) {
    return z > 0.f ? z : (__expf(z) - 1.f);
}
// 16-lane sum on the VALU pipe (DPP): quad_perm xor1/xor2, row_half_mirror, row_mirror.
__device__ __forceinline__ float dpp_sum16(float v) {
    int t;
    t = __builtin_amdgcn_mov_dpp(__float_as_int(v), 0xB1, 0xF, 0xF, true);
    v += __int_as_float(t);
    t = __builtin_amdgcn_mov_dpp(__float_as_int(v), 0x4E, 0xF, 0xF, true);
    v += __int_as_float(t);
    t = __builtin_amdgcn_mov_dpp(__float_as_int(v), 0x141, 0xF, 0xF, true);
    v += __int_as_float(t);
    t = __builtin_amdgcn_mov_dpp(__float_as_int(v), 0x140, 0xF, 0xF, true);
    v += __int_as_float(t);
    return v;
}
// async global->LDS, 16B per lane; lds base must be wave-uniform (HW adds lane*16)
__device__ __forceinline__ void gload16(const unsigned short* g, unsigned short* l) {
    __builtin_amdgcn_global_load_lds(
        (const __attribute__((address_space(1))) unsigned int*)(const void*)g,
        (__attribute__((address_space(3))) unsigned int*)(void*)l, 16, 0, 0);
}

// ---------------------------------------------------------------- prep: cvt x | pack W | degree
__global__ __launch_bounds__(256) void prep(
    const float* __restrict__ x,
    const float* __restrict__ Wq, const float* __restrict__ Wk,
    const float* __restrict__ Wv, const float* __restrict__ Ws,
    const float* __restrict__ bq, const float* __restrict__ bk,
    const float* __restrict__ bv, const float* __restrict__ bs,
    const int* __restrict__ ei,
    unsigned short* __restrict__ xb, unsigned short* __restrict__ WALL,
    float* __restrict__ BALL, int* __restrict__ degi)
{
    const int b = blockIdx.x;
    if (b < PREP_CVT_BLKS) {
        int i = b * 256 + threadIdx.x;           // over 320000
        float4 v0 = ldf4(x + (size_t)i * 8);
        float4 v1 = ldf4(x + (size_t)i * 8 + 4);
        ushort4 o0, o1;
        o0.x = f2h(v0.x); o0.y = f2h(v0.y); o0.z = f2h(v0.z); o0.w = f2h(v0.w);
        o1.x = f2h(v1.x); o1.y = f2h(v1.y); o1.z = f2h(v1.z); o1.w = f2h(v1.w);
        *reinterpret_cast<ushort4*>(xb + (size_t)i * 8) = o0;
        *reinterpret_cast<ushort4*>(xb + (size_t)i * 8 + 4) = o1;
    } else if (b < PREP_CVT_BLKS + PREP_PACK_BLKS) {
        int i = (b - PREP_CVT_BLKS) * 256 + threadIdx.x;  // over 131072
        int J = i >> 5;
        int kk = (i & 31) * 8;
        int mat = J >> 10, c = (J >> 8) & 3, jj = J & 255;
        const float* W = (mat == 0) ? Wq : (mat == 1) ? Wk : (mat == 2) ? Wv : Ws;
        const float* src = W + (size_t)c * 65536 + jj * 256 + kk;
        float4 v0 = ldf4(src);
        float4 v1 = ldf4(src + 4);
        ushort4 o0, o1;
        o0.x = f2h(v0.x); o0.y = f2h(v0.y); o0.z = f2h(v0.z); o0.w = f2h(v0.w);
        o1.x = f2h(v1.x); o1.y = f2h(v1.y); o1.z = f2h(v1.z); o1.w = f2h(v1.w);
        *reinterpret_cast<ushort4*>(WALL + (size_t)J * 256 + kk) = o0;
        *reinterpret_cast<ushort4*>(WALL + (size_t)J * 256 + kk + 4) = o1;
        if (kk == 0) {
            const float* bb = (mat == 0) ? bq : (mat == 1) ? bk : (mat == 2) ? bv : bs;
            BALL[J] = bb[c * 256 + jj];
        }
    } else {
        int e = (b - PREP_CVT_BLKS - PREP_PACK_BLKS) * 256 + threadIdx.x;
        if (e < N_EDGES) atomicAdd(&degi[ei[N_EDGES + e]], 1);
    }
}

// ---------------------------------------------------------------- prefix sum (1 block, 1024 thr)
__global__ __launch_bounds__(1024) void scan_kernel(const int* __restrict__ degi,
                                                    int* __restrict__ rowptr,
                                                    int* __restrict__ cursor) {
    __shared__ int part[1024];
    int t = threadIdx.x;
    int base = t * 10;
    int s = 0;
    #pragma unroll
    for (int i = 0; i < 10; ++i) { int idx = base + i; if (idx < N_NODES) s += degi[idx]; }
    part[t] = s;
    __syncthreads();
    for (int off = 1; off < 1024; off <<= 1) {
        int v = part[t];
        int u = (t >= off) ? part[t - off] : 0;
        __syncthreads();
        part[t] = v + u;
        __syncthreads();
    }
    int run = (t == 0) ? 0 : part[t - 1];
    #pragma unroll
    for (int i = 0; i < 10; ++i) {
        int idx = base + i;
        if (idx < N_NODES) { rowptr[idx] = run; cursor[idx] = run; run += degi[idx]; }
    }
    if (t == 1023) rowptr[N_NODES] = N_EDGES;
}

// ---------------------------------------------------------------- band GEMM + CSR scatter
// blocks [0, GEMM_BLKS): block = (bm row-tile, bn band of 4 tiles).
//   A-tile (128 x 256 = 64 KB f16) staged ONCE into LDS, reused across the band's
//   4 bn tiles -> staged bytes 324 -> 202 MB (A was re-staged 32x before).
//   A swizzle: 32 chunks/row, slot ch holds global chunk ch^(row&31) (involution).
// blocks [GEMM_BLKS, +SCAT_BLKS): CSR scatter (backfills CU slack).
__global__ __launch_bounds__(256) void gemm_scatter(
    const unsigned short* __restrict__ xb, const unsigned short* __restrict__ WALL,
    const float* __restrict__ BALL, unsigned short* __restrict__ QKVS,
    const int* __restrict__ ei, int* __restrict__ cursor,
    int* __restrict__ csr_eid, int* __restrict__ csr_src)
{
    if (blockIdx.x >= GEMM_BLKS) {
        int e = (blockIdx.x - GEMM_BLKS) * 256 + threadIdx.x;
        if (e < N_EDGES) {
            int d = ei[N_EDGES + e];
            int p = atomicAdd(&cursor[d], 1);
            csr_eid[p] = e;
            csr_src[p] = ei[e];
        }
        return;
    }

    __shared__ __align__(16) unsigned short Ar[BM * DIM];   // 64 KB, full-K A tile
    __shared__ __align__(16) unsigned short Bs[128 * 64];   // 16 KB, one bn-tile k-chunk

    const int bid  = blockIdx.x;
    const int m    = bid % NTM;          // A row-tile
    const int band = bid / NTM;          // bn band (4 tiles of 128)
    const int bm   = m * BM;

    const int tid = threadIdx.x, w = tid >> 6, lane = tid & 63;
    const int il = lane & 15, kg = lane >> 4;
    const int wr = w >> 1, wc = w & 1;

    // ---- stage A once: 4096 slots of 16B, 16 rounds x 256 threads
    #pragma unroll
    for (int rnd = 0; rnd < 16; ++rnd) {
        const int sidx = rnd * 256 + tid;
        const int row = sidx >> 5, ch = sidx & 31;
        const int dc = ch ^ (row & 31);
        int ar = bm + row; ar = ar < N_NODES ? ar : N_NODES - 1;
        gload16(xb + (size_t)ar * DIM + dc * 8, Ar + sidx * 8 - lane * 8);
    }
    __syncthreads();   // A resident (compiler drains vmcnt at barrier)

    const f4v zero = {0.f, 0.f, 0.f, 0.f};
    for (int t = 0; t < TPB; ++t) {
        const int bn = (band * TPB + t) * 128;
        f4v acc[4][4];
        #pragma unroll
        for (int mi = 0; mi < 4; ++mi)
            #pragma unroll
            for (int ni = 0; ni < 4; ++ni) acc[mi][ni] = zero;

        for (int k0 = 0; k0 < 4; ++k0) {             // 64-k steps
            // stage B(bn, k0): 1024 slots, ch^(row&7) swizzle (proven R14 form)
            #pragma unroll
            for (int r4 = 0; r4 < 4; ++r4) {
                const int sidx = r4 * 256 + tid;
                const int row = sidx >> 3, ch = sidx & 7;
                const int dc = ch ^ (row & 7);
                gload16(WALL + (size_t)(bn + row) * DIM + k0 * 64 + dc * 8,
                        Bs + sidx * 8 - lane * 8);
            }
            __syncthreads();

            #pragma unroll
            for (int kk = 0; kk < 2; ++kk) {          // two 32-k sub-steps
                const int ks = k0 * 2 + kk;           // global 32-k step, 0..7
                h8v a[4], b[4];
                #pragma unroll
                for (int mi = 0; mi < 4; ++mi) {
                    const int row = wr * 64 + mi * 16 + il;
                    const int ch = (ks * 4 + kg) ^ (row & 31);
                    a[mi] = *reinterpret_cast<const h8v*>(&Ar[row * DIM + ch * 8]);
                }
                #pragma unroll
                for (int ni = 0; ni < 4; ++ni) {
                    const int row = wc * 64 + ni * 16 + il;
                    const int c2 = (kk * 4 + kg) ^ (row & 7);
                    b[ni] = *reinterpret_cast<const h8v*>(&Bs[row * 64 + c2 * 8]);
                }
                #pragma unroll
                for (int mi = 0; mi < 4; ++mi)
                    #pragma unroll
                    for (int ni = 0; ni < 4; ++ni)
                        acc[mi][ni] = __builtin_amdgcn_mfma_f32_16x16x32_f16(a[mi], b[ni], acc[mi][ni], 0, 0, 0);
            }
            __syncthreads();   // Bs reads done before next stage
        }

        // Epilogue for this bn tile. D layout: col = lane&15, row = (lane>>4)*4 + rr
        #pragma unroll
        for (int ni = 0; ni < 4; ++ni) {
            const int col = bn + wc * 64 + ni * 16 + il;   // 0..4095
            const float bia = BALL[col];
            const int mat = col >> 10;
            const int cj = col & 1023;                      // c*256 + j
            const int cc = cj >> 8, jj = cj & 255;
            #pragma unroll
            for (int mi = 0; mi < 4; ++mi) {
                const int rbase = bm + wr * 64 + mi * 16 + kg * 4;
                #pragma unroll
                for (int rr = 0; rr < 4; ++rr) {
                    const int r = rbase + rr;
                    if (r < N_NODES)
                        QKVS[(((size_t)r * NCH + cc) * 4 + mat) * DIM + jj] =
                            f2h(acc[mi][ni][rr] + bia);
                }
            }
        }
    }
}

// ---------------------------------------------------------------- fused CSR edge pass + node MLP + edge MLP
// block = one dst node, wave = one channel. f16 QKVS; dots via v_dot2_f32_f16.
__global__ __launch_bounds__(256) void edge_fused(
    const int* __restrict__ rowptr, const int* __restrict__ csr_eid,
    const int* __restrict__ csr_src,
    const float* __restrict__ adj, const float* __restrict__ We,
    const unsigned short* __restrict__ QKVS,
    const float* __restrict__ W1, const float* __restrict__ b1,
    const float* __restrict__ W2, const float* __restrict__ b2,
    const float* __restrict__ Wm1, const float* __restrict__ bm1,
    const float* __restrict__ Wm2, const float* __restrict__ bm2,
    const float* __restrict__ Wm3, const float* __restrict__ bm3,
    float* __restrict__ out, float* __restrict__ mlpout)
{
    __shared__ __align__(16) float xc[NCH * DIM];   // 4 KB
    __shared__ float hh[HIDD];
    __shared__ float alpha_s[NCH][MAXDEG];          // 5 KB
    __shared__ float av_s[NCH][MAXDEG];             // 5 KB

    const int n = blockIdx.x;
    const int tid = threadIdx.x;
    const int c = tid >> 6, lane = tid & 63, col = lane * 4;

    const size_t nbase = ((size_t)n * NCH + c) * 4 * DIM;
    const uint2 qdu = *reinterpret_cast<const uint2*>(QKVS + nbase + col);
    const uint2 kdu = *reinterpret_cast<const uint2*>(QKVS + nbase + DIM + col);
    float4 we = ldf4(&We[c * DIM + col]);

    // qd unpacked once for the q.we dot (f32 path)
    h2v qd0 = u2h2(qdu.x), qd1 = u2h2(qdu.y);
    float qdwe = dpp_sum16((float)qd0.x * we.x + (float)qd0.y * we.y +
                           (float)qd1.x * we.z + (float)qd1.y * we.w);

    const float* adjc = adj + (size_t)c * N_EDGES;
    float4 acc = make_float4(0.f, 0.f, 0.f, 0.f);
    const int p0 = rowptr[n], p1 = rowptr[n + 1];
    const int deg = p1 - p0;
    for (int p = p0; p < p1; ++p) {
        int eid = csr_eid[p];
        int s   = csr_src[p];
        float av = adjc[eid];
        const size_t sbase = ((size_t)s * NCH + c) * 4 * DIM;
        const uint2 qsu = *reinterpret_cast<const uint2*>(QKVS + sbase + col);
        const uint2 ksu = *reinterpret_cast<const uint2*>(QKVS + sbase + DIM + col);
        const uint2 vsu = *reinterpret_cast<const uint2*>(QKVS + sbase + 2 * DIM + col);
        float d1 = dpp_sum16(dot4h(qdu, ksu, 0.f));
        float d2 = dpp_sum16(dot4h(qsu, kdu, 0.f));
        d1 += av * qdwe;
        float al = 0.5f * (fast_tanh(d1 * 0.125f) + fast_tanh(d2 * 0.125f));
        al += __shfl_xor(al, 16, 64);
        al += __shfl_xor(al, 32, 64);
        int ep = p - p0;
        if (lane == 0 && ep < MAXDEG) {
            alpha_s[c][ep] = al * 0.25f;
            av_s[c][ep]    = av;
        }
        h2v vs0 = u2h2(vsu.x), vs1 = u2h2(vsu.y);
        acc.x += av * (float)vs0.x; acc.y += av * (float)vs0.y;
        acc.z += av * (float)vs1.x; acc.w += av * (float)vs1.y;
    }
    // x_cat[c][col..col+3] = skip(f16) + agg/cnt
    float inv = 1.0f / fmaxf((float)deg, 1.0f);
    const uint2 sku = *reinterpret_cast<const uint2*>(QKVS + nbase + 3 * DIM + col);
    h2v sk0 = u2h2(sku.x), sk1 = u2h2(sku.y);
    float4 xv;
    xv.x = (float)sk0.x + acc.x * we.x * inv; xv.y = (float)sk0.y + acc.y * we.y * inv;
    xv.z = (float)sk1.x + acc.z * we.z * inv; xv.w = (float)sk1.y + acc.w * we.w * inv;
    *reinterpret_cast<float4*>(&xc[c * DIM + col]) = xv;
    __syncthreads();

    // node MLP phase 1: h[row] = elu(b1[row] + dot(xc, W1[row])); row = tid>>5, 32 lanes each
    {
        const int row = tid >> 5, l32 = tid & 31;
        const float* w1r = W1 + row * (NCH * DIM);
        float p = 0.f;
        #pragma unroll
        for (int k2 = 0; k2 < 32; ++k2) {
            int i = l32 + 32 * k2;
            p += xc[i] * w1r[i];
        }
        p = dpp_sum16(p);
        p += __shfl_xor(p, 16, 64);      // 32-lane total (within each wave half)
        if (l32 == 0) hh[row] = fast_elu(p + b1[row]);
    }
    __syncthreads();

    // node MLP phase 2: out[n][tid] = tanh(b2 + h . W2[tid])
    {
        float z = b2[tid];
        #pragma unroll
        for (int k = 0; k < HIDD; ++k) z += hh[k] * W2[tid * HIDD + k];
        out[(size_t)n * DIM + tid] = fast_tanh(z);
    }

    // edge MLP (8->8->8->4): one thread per edge of this row (alpha/adj from LDS)
    for (int ep = tid; ep < deg; ep += 256) {
        const int eid = csr_eid[p0 + ep];
        float in[8];
        #pragma unroll
        for (int cc = 0; cc < NCH; ++cc) {
            in[cc]     = (ep < MAXDEG) ? alpha_s[cc][ep] : 0.f;
            in[4 + cc] = (ep < MAXDEG) ? av_s[cc][ep]    : 0.f;
        }
        float h1[8], h2[8];
        #pragma unroll
        for (int j = 0; j < 8; ++j) {
            float z = bm1[j];
            #pragma unroll
            for (int i = 0; i < 8; ++i) z += Wm1[j*8 + i] * in[i];
            h1[j] = fast_elu(z);
        }
        #pragma unroll
        for (int j = 0; j < 8; ++j) {
            float z = bm2[j];
            #pragma unroll
            for (int i = 0; i < 8; ++i) z += Wm2[j*8 + i] * h1[i];
            h2[j] = fast_elu(z);
        }
        #pragma unroll
        for (int o = 0; o < 4; ++o) {
            float z = bm3[o];
            #pragma unroll
            for (int j = 0; j < 8; ++j) z += Wm3[o*8 + j] * h2[j];
            mlpout[(size_t)o * N_EDGES + eid] = z;
        }
    }
}

// ---------------------------------------------------------------- launch
extern "C" void kernel_launch(void* const* d_in, const int* in_sizes, int n_in,
                              void* d_out, int out_size, void* d_ws, size_t ws_size,
                              hipStream_t stream) {
    const float* x    = (const float*)d_in[0];
    const int*   ei   = (const int*)  d_in[1];
    const float* adj  = (const float*)d_in[2];
    const float* Wq   = (const float*)d_in[4];
    const float* bq   = (const float*)d_in[5];
    const float* Wk   = (const float*)d_in[6];
    const float* bk   = (const float*)d_in[7];
    const float* Wv   = (const float*)d_in[8];
    const float* bv   = (const float*)d_in[9];
    const float* We   = (const float*)d_in[10];
    const float* Wsk  = (const float*)d_in[11];
    const float* bsk  = (const float*)d_in[12];
    const float* Wmc1 = (const float*)d_in[13];
    const float* bmc1 = (const float*)d_in[14];
    const float* Wmc2 = (const float*)d_in[15];
    const float* bmc2 = (const float*)d_in[16];
    const float* Wm1  = (const float*)d_in[17];
    const float* bm1  = (const float*)d_in[18];
    const float* Wm2  = (const float*)d_in[19];
    const float* bm2  = (const float*)d_in[20];
    const float* Wm3  = (const float*)d_in[21];
    const float* bm3  = (const float*)d_in[22];

    // ---- workspace layout (~90 MB total)
    char* w = (char*)d_ws;
    unsigned short* xb   = (unsigned short*)w; w += (size_t)N_NODES * DIM * 2;        // 5.12 MB
    unsigned short* WALL = (unsigned short*)w; w += (size_t)4096 * DIM * 2;           // 2.10 MB
    float*          BALL = (float*)w;          w += (size_t)4096 * 4;                 // 16 KB
    unsigned short* QKVS = (unsigned short*)w; w += (size_t)N_NODES * NCH * 4 * DIM * 2; // 81.92 MB
    int* degi    = (int*)w; w += N_NODES * 4;
    int* rowptr  = (int*)w; w += (N_NODES + 1) * 4;
    int* cursor  = (int*)w; w += N_NODES * 4;
    int* csr_eid = (int*)w; w += N_EDGES * 4;
    int* csr_src = (int*)w; w += N_EDGES * 4;

    float* xout   = (float*)d_out;
    float* mlpout = xout + (size_t)N_NODES * DIM;

    // ---- fused prep (cvt x + pack W + degree) ; degi must be zeroed first
    hipMemsetAsync(degi, 0, N_NODES * sizeof(int), stream);
    prep<<<PREP_CVT_BLKS + PREP_PACK_BLKS + PREP_DEG_BLKS, 256, 0, stream>>>(
        x, Wq, Wk, Wv, Wsk, bq, bk, bv, bsk, ei, xb, WALL, BALL, degi);

    // ---- prefix sum
    scan_kernel<<<1, 1024, 0, stream>>>(degi, rowptr, cursor);

    // ---- band GEMM (A-resident LDS) + CSR scatter in one launch
    gemm_scatter<<<GEMM_BLKS + SCAT_BLKS, 256, 0, stream>>>(xb, WALL, BALL, QKVS,
                                                            ei, cursor, csr_eid, csr_src);

    // ---- fused edge pass + node MLP + edge MLP: writes both outputs directly
    edge_fused<<<N_NODES, 256, 0, stream>>>(rowptr, csr_eid, csr_src, adj, We,
                                            QKVS, Wmc1, bmc1, Wmc2, bmc2,
                                            Wm1, bm1, Wm2, bm2, Wm3, bm3,
                                            xout, mlpout);
}

// Round 21
// 202.226 us; speedup vs baseline: 1.1544x; 1.1544x over previous
//
#include <hip/hip_runtime.h>
#include <math.h>

#define N_NODES 10000
#define N_EDGES 100000
#define DIM 256
#define NCH 4
#define HIDD 8
#define OUTD 4

#define BM 128
#define BN 128
#define BK 64
#define NTM 79              // ceil(10000/128)
#define NTN 32              // 4096/128
#define NWG (NTM * NTN)     // 2528, divisible by 8
#define CPX (NWG / 8)       // 316
#define SCAT_BLKS 391       // ceil(100000/256), appended to gemm launch

// prep kernel block ranges
#define PREP_CVT_BLKS 1250  // 10000*256/8 / 256
#define PREP_PACK_BLKS 512
#define PREP_DEG_BLKS 391   // ceil(100000/256)

#define MAXDEG 320          // Poisson(10) max deg ~40; 8x safety for LDS alpha stash

typedef _Float16 h8v __attribute__((ext_vector_type(8)));  // 8 f16 in 4 VGPRs (MFMA frag)
typedef _Float16 h2v __attribute__((ext_vector_type(2)));  // packed pair for v_dot2
typedef float f4v __attribute__((ext_vector_type(4)));     // MFMA accumulator

__device__ __forceinline__ float4 ldf4(const float* p) {
    return *reinterpret_cast<const float4*>(p);
}
__device__ __forceinline__ unsigned short f2h(float f) {   // f32 -> f16 (RNE via HW cvt)
    _Float16 h = (_Float16)f;
    return __builtin_bit_cast(unsigned short, h);
}
__device__ __forceinline__ h2v u2h2(unsigned int u) {
    return __builtin_bit_cast(h2v, u);
}
// 4-element f16 dot with f32 accumulate; v_dot2_f32_f16 if available
__device__ __forceinline__ float dot4h(uint2 a, uint2 b, float acc) {
#if __has_builtin(__builtin_amdgcn_fdot2)
    acc = __builtin_amdgcn_fdot2(u2h2(a.x), u2h2(b.x), acc, false);
    acc = __builtin_amdgcn_fdot2(u2h2(a.y), u2h2(b.y), acc, false);
#else
    h2v ax = u2h2(a.x), ay = u2h2(a.y), bx = u2h2(b.x), by = u2h2(b.y);
    acc += (float)ax.x*(float)bx.x + (float)ax.y*(float)bx.y
         + (float)ay.x*(float)by.x + (float)ay.y*(float)by.y;
#endif
    return acc;
}
// fast tanh: (e-1)/(e+1), e=exp(2x)
__device__ __forceinline__ float fast_tanh(float x) {
    float xc = fminf(fmaxf(x, -15.f), 15.f);
    float e = __expf(2.f * xc);
    return (e - 1.f) * __builtin_amdgcn_rcpf(e + 1.f);
}
__device__ __forceinline__ float fast_elu(float z) {
    return z > 0.f ? z : (__expf(z) - 1.f);
}
// 16-lane sum on the VALU pipe (DPP): quad_perm xor1/xor2, row_half_mirror, row_mirror.
__device__ __forceinline__ float dpp_sum16(float v) {
    int t;
    t = __builtin_amdgcn_mov_dpp(__float_as_int(v), 0xB1, 0xF, 0xF, true);
    v += __int_as_float(t);
    t = __builtin_amdgcn_mov_dpp(__float_as_int(v), 0x4E, 0xF, 0xF, true);
    v += __int_as_float(t);
    t = __builtin_amdgcn_mov_dpp(__float_as_int(v), 0x141, 0xF, 0xF, true);
    v += __int_as_float(t);
    t = __builtin_amdgcn_mov_dpp(__float_as_int(v), 0x140, 0xF, 0xF, true);
    v += __int_as_float(t);
    return v;
}
// async global->LDS, 16B per lane; lds base must be wave-uniform (HW adds lane*16)
__device__ __forceinline__ void gload16(const unsigned short* g, unsigned short* l) {
    __builtin_amdgcn_global_load_lds(
        (const __attribute__((address_space(1))) unsigned int*)(const void*)g,
        (__attribute__((address_space(3))) unsigned int*)(void*)l, 16, 0, 0);
}

// ---------------------------------------------------------------- prep: cvt x | pack W | degree
__global__ __launch_bounds__(256) void prep(
    const float* __restrict__ x,
    const float* __restrict__ Wq, const float* __restrict__ Wk,
    const float* __restrict__ Wv, const float* __restrict__ Ws,
    const float* __restrict__ bq, const float* __restrict__ bk,
    const float* __restrict__ bv, const float* __restrict__ bs,
    const int* __restrict__ ei,
    unsigned short* __restrict__ xb, unsigned short* __restrict__ WALL,
    float* __restrict__ BALL, int* __restrict__ degi)
{
    const int b = blockIdx.x;
    if (b < PREP_CVT_BLKS) {
        int i = b * 256 + threadIdx.x;           // over 320000
        float4 v0 = ldf4(x + (size_t)i * 8);
        float4 v1 = ldf4(x + (size_t)i * 8 + 4);
        ushort4 o0, o1;
        o0.x = f2h(v0.x); o0.y = f2h(v0.y); o0.z = f2h(v0.z); o0.w = f2h(v0.w);
        o1.x = f2h(v1.x); o1.y = f2h(v1.y); o1.z = f2h(v1.z); o1.w = f2h(v1.w);
        *reinterpret_cast<ushort4*>(xb + (size_t)i * 8) = o0;
        *reinterpret_cast<ushort4*>(xb + (size_t)i * 8 + 4) = o1;
    } else if (b < PREP_CVT_BLKS + PREP_PACK_BLKS) {
        int i = (b - PREP_CVT_BLKS) * 256 + threadIdx.x;  // over 131072
        int J = i >> 5;
        int kk = (i & 31) * 8;
        int mat = J >> 10, c = (J >> 8) & 3, jj = J & 255;
        const float* W = (mat == 0) ? Wq : (mat == 1) ? Wk : (mat == 2) ? Wv : Ws;
        const float* src = W + (size_t)c * 65536 + jj * 256 + kk;
        float4 v0 = ldf4(src);
        float4 v1 = ldf4(src + 4);
        ushort4 o0, o1;
        o0.x = f2h(v0.x); o0.y = f2h(v0.y); o0.z = f2h(v0.z); o0.w = f2h(v0.w);
        o1.x = f2h(v1.x); o1.y = f2h(v1.y); o1.z = f2h(v1.z); o1.w = f2h(v1.w);
        *reinterpret_cast<ushort4*>(WALL + (size_t)J * 256 + kk) = o0;
        *reinterpret_cast<ushort4*>(WALL + (size_t)J * 256 + kk + 4) = o1;
        if (kk == 0) {
            const float* bb = (mat == 0) ? bq : (mat == 1) ? bk : (mat == 2) ? bv : bs;
            BALL[J] = bb[c * 256 + jj];
        }
    } else {
        int e = (b - PREP_CVT_BLKS - PREP_PACK_BLKS) * 256 + threadIdx.x;
        if (e < N_EDGES) atomicAdd(&degi[ei[N_EDGES + e]], 1);
    }
}

// ---------------------------------------------------------------- prefix sum (1 block, 1024 thr)
__global__ __launch_bounds__(1024) void scan_kernel(const int* __restrict__ degi,
                                                    int* __restrict__ rowptr,
                                                    int* __restrict__ cursor) {
    __shared__ int part[1024];
    int t = threadIdx.x;
    int base = t * 10;
    int s = 0;
    #pragma unroll
    for (int i = 0; i < 10; ++i) { int idx = base + i; if (idx < N_NODES) s += degi[idx]; }
    part[t] = s;
    __syncthreads();
    for (int off = 1; off < 1024; off <<= 1) {
        int v = part[t];
        int u = (t >= off) ? part[t - off] : 0;
        __syncthreads();
        part[t] = v + u;
        __syncthreads();
    }
    int run = (t == 0) ? 0 : part[t - 1];
    #pragma unroll
    for (int i = 0; i < 10; ++i) {
        int idx = base + i;
        if (idx < N_NODES) { rowptr[idx] = run; cursor[idx] = run; run += degi[idx]; }
    }
    if (t == 1023) rowptr[N_NODES] = N_EDGES;
}

// ---------------------------------------------------------------- fused MFMA GEMM + CSR scatter
// blocks [0,NWG): GEMM C[10000][4096] = xb . WALL^T (+BALL) -> QKVS f16.
// blocks [NWG, NWG+SCAT_BLKS): CSR scatter (independent work, hides under gemm).
__global__ __launch_bounds__(256) void gemm_scatter(
    const unsigned short* __restrict__ xb, const unsigned short* __restrict__ WALL,
    const float* __restrict__ BALL, unsigned short* __restrict__ QKVS,
    const int* __restrict__ ei, int* __restrict__ cursor,
    int* __restrict__ csr_eid, int* __restrict__ csr_src)
{
    if (blockIdx.x >= NWG) {
        int e = (blockIdx.x - NWG) * 256 + threadIdx.x;
        if (e < N_EDGES) {
            int d = ei[N_EDGES + e];
            int p = atomicAdd(&cursor[d], 1);
            csr_eid[p] = e;
            csr_src[p] = ei[e];
        }
        return;
    }

    __shared__ __align__(16) unsigned short As[BM * BK];   // 16 KB
    __shared__ __align__(16) unsigned short Bs[BN * BK];   // 16 KB

    const int bid = blockIdx.x;
    const int f = (bid & 7) * CPX + (bid >> 3);   // XCD swizzle: bijective (2528 % 8 == 0)
    const int bm = (f >> 5) * BM, bn = (f & 31) * BN;

    const int tid = threadIdx.x, w = tid >> 6, lane = tid & 63;
    const int il = lane & 15, kg = lane >> 4;
    const int wr = w >> 1, wc = w & 1;

    const f4v zero = {0.f, 0.f, 0.f, 0.f};
    f4v acc[4][4];
    #pragma unroll
    for (int mi = 0; mi < 4; ++mi)
        #pragma unroll
        for (int ni = 0; ni < 4; ++ni) acc[mi][ni] = zero;

    for (int k0 = 0; k0 < DIM; k0 += BK) {
        // stage: sidx in [0,1024): row = sidx>>3, ch = sidx&7; slot holds chunk ch^(row&7)
        #pragma unroll
        for (int t = 0; t < 4; ++t) {
            const int sidx = tid + t * 256;
            const int row = sidx >> 3, ch = sidx & 7;
            const int dc = ch ^ (row & 7);
            const int ldsbase = sidx * 8 - lane * 8;      // wave-uniform base (lane*16B added by HW)
            int ar = bm + row; ar = ar < N_NODES ? ar : N_NODES - 1;
            gload16(xb + (size_t)ar * DIM + k0 + dc * 8, As + ldsbase);
            gload16(WALL + (size_t)(bn + row) * DIM + k0 + dc * 8, Bs + ldsbase);
        }
        __syncthreads();   // compiler drains vmcnt before s_barrier

        #pragma unroll
        for (int kk = 0; kk < 2; ++kk) {                  // two K=32 sub-steps per tile
            h8v a[4], b[4];
            #pragma unroll
            for (int mi = 0; mi < 4; ++mi) {
                const int row = wr * 64 + mi * 16 + il;
                const int c2 = (kk * 4 + kg) ^ (row & 7);
                a[mi] = *reinterpret_cast<const h8v*>(&As[row * 64 + c2 * 8]);
            }
            #pragma unroll
            for (int ni = 0; ni < 4; ++ni) {
                const int row = wc * 64 + ni * 16 + il;
                const int c2 = (kk * 4 + kg) ^ (row & 7);
                b[ni] = *reinterpret_cast<const h8v*>(&Bs[row * 64 + c2 * 8]);
            }
            #pragma unroll
            for (int mi = 0; mi < 4; ++mi)
                #pragma unroll
                for (int ni = 0; ni < 4; ++ni)
                    acc[mi][ni] = __builtin_amdgcn_mfma_f32_16x16x32_f16(a[mi], b[ni], acc[mi][ni], 0, 0, 0);
        }
        __syncthreads();
    }

    // Epilogue. D layout: col = lane&15, row(local) = (lane>>4)*4 + rr  [guide §3, m89/m91]
    #pragma unroll
    for (int ni = 0; ni < 4; ++ni) {
        const int col = bn + wc * 64 + ni * 16 + il;       // 0..4095
        const float bia = BALL[col];
        const int mat = col >> 10;
        const int cj = col & 1023;                          // c*256 + j
        const int cc = cj >> 8, jj = cj & 255;
        #pragma unroll
        for (int mi = 0; mi < 4; ++mi) {
            const int rbase = bm + wr * 64 + mi * 16 + kg * 4;
            #pragma unroll
            for (int rr = 0; rr < 4; ++rr) {
                const int r = rbase + rr;
                if (r < N_NODES)
                    QKVS[(((size_t)r * NCH + cc) * 4 + mat) * DIM + jj] =
                        f2h(acc[mi][ni][rr] + bia);
            }
        }
    }
}

// ---------------------------------------------------------------- fused CSR edge pass + node MLP + edge MLP
// block = one dst node, wave = one channel. f16 QKVS; dots via v_dot2_f32_f16.
__global__ __launch_bounds__(256) void edge_fused(
    const int* __restrict__ rowptr, const int* __restrict__ csr_eid,
    const int* __restrict__ csr_src,
    const float* __restrict__ adj, const float* __restrict__ We,
    const unsigned short* __restrict__ QKVS,
    const float* __restrict__ W1, const float* __restrict__ b1,
    const float* __restrict__ W2, const float* __restrict__ b2,
    const float* __restrict__ Wm1, const float* __restrict__ bm1,
    const float* __restrict__ Wm2, const float* __restrict__ bm2,
    const float* __restrict__ Wm3, const float* __restrict__ bm3,
    float* __restrict__ out, float* __restrict__ mlpout)
{
    __shared__ __align__(16) float xc[NCH * DIM];   // 4 KB
    __shared__ float hh[HIDD];
    __shared__ float alpha_s[NCH][MAXDEG];          // 5 KB
    __shared__ float av_s[NCH][MAXDEG];             // 5 KB

    const int n = blockIdx.x;
    const int tid = threadIdx.x;
    const int c = tid >> 6, lane = tid & 63, col = lane * 4;

    const size_t nbase = ((size_t)n * NCH + c) * 4 * DIM;
    const uint2 qdu = *reinterpret_cast<const uint2*>(QKVS + nbase + col);
    const uint2 kdu = *reinterpret_cast<const uint2*>(QKVS + nbase + DIM + col);
    float4 we = ldf4(&We[c * DIM + col]);

    // qd unpacked once for the q.we dot (f32 path)
    h2v qd0 = u2h2(qdu.x), qd1 = u2h2(qdu.y);
    float qdwe = dpp_sum16((float)qd0.x * we.x + (float)qd0.y * we.y +
                           (float)qd1.x * we.z + (float)qd1.y * we.w);

    const float* adjc = adj + (size_t)c * N_EDGES;
    float4 acc = make_float4(0.f, 0.f, 0.f, 0.f);
    const int p0 = rowptr[n], p1 = rowptr[n + 1];
    const int deg = p1 - p0;
    for (int p = p0; p < p1; ++p) {
        int eid = csr_eid[p];
        int s   = csr_src[p];
        float av = adjc[eid];
        const size_t sbase = ((size_t)s * NCH + c) * 4 * DIM;
        const uint2 qsu = *reinterpret_cast<const uint2*>(QKVS + sbase + col);
        const uint2 ksu = *reinterpret_cast<const uint2*>(QKVS + sbase + DIM + col);
        const uint2 vsu = *reinterpret_cast<const uint2*>(QKVS + sbase + 2 * DIM + col);
        float d1 = dpp_sum16(dot4h(qdu, ksu, 0.f));
        float d2 = dpp_sum16(dot4h(qsu, kdu, 0.f));
        d1 += av * qdwe;
        float al = 0.5f * (fast_tanh(d1 * 0.125f) + fast_tanh(d2 * 0.125f));
        al += __shfl_xor(al, 16, 64);
        al += __shfl_xor(al, 32, 64);
        int ep = p - p0;
        if (lane == 0 && ep < MAXDEG) {
            alpha_s[c][ep] = al * 0.25f;
            av_s[c][ep]    = av;
        }
        h2v vs0 = u2h2(vsu.x), vs1 = u2h2(vsu.y);
        acc.x += av * (float)vs0.x; acc.y += av * (float)vs0.y;
        acc.z += av * (float)vs1.x; acc.w += av * (float)vs1.y;
    }
    // x_cat[c][col..col+3] = skip(f16) + agg/cnt
    float inv = 1.0f / fmaxf((float)deg, 1.0f);
    const uint2 sku = *reinterpret_cast<const uint2*>(QKVS + nbase + 3 * DIM + col);
    h2v sk0 = u2h2(sku.x), sk1 = u2h2(sku.y);
    float4 xv;
    xv.x = (float)sk0.x + acc.x * we.x * inv; xv.y = (float)sk0.y + acc.y * we.y * inv;
    xv.z = (float)sk1.x + acc.z * we.z * inv; xv.w = (float)sk1.y + acc.w * we.w * inv;
    *reinterpret_cast<float4*>(&xc[c * DIM + col]) = xv;
    __syncthreads();

    // node MLP phase 1: h[row] = elu(b1[row] + dot(xc, W1[row])); row = tid>>5, 32 lanes each
    {
        const int row = tid >> 5, l32 = tid & 31;
        const float* w1r = W1 + row * (NCH * DIM);
        float p = 0.f;
        #pragma unroll
        for (int k2 = 0; k2 < 32; ++k2) {
            int i = l32 + 32 * k2;
            p += xc[i] * w1r[i];
        }
        p = dpp_sum16(p);
        p += __shfl_xor(p, 16, 64);      // 32-lane total (within each wave half)
        if (l32 == 0) hh[row] = fast_elu(p + b1[row]);
    }
    __syncthreads();

    // node MLP phase 2: out[n][tid] = tanh(b2 + h . W2[tid])
    {
        float z = b2[tid];
        #pragma unroll
        for (int k = 0; k < HIDD; ++k) z += hh[k] * W2[tid * HIDD + k];
        out[(size_t)n * DIM + tid] = fast_tanh(z);
    }

    // edge MLP (8->8->8->4): one thread per edge of this row (alpha/adj from LDS)
    for (int ep = tid; ep < deg; ep += 256) {
        const int eid = csr_eid[p0 + ep];
        float in[8];
        #pragma unroll
        for (int cc = 0; cc < NCH; ++cc) {
            in[cc]     = (ep < MAXDEG) ? alpha_s[cc][ep] : 0.f;
            in[4 + cc] = (ep < MAXDEG) ? av_s[cc][ep]    : 0.f;
        }
        float h1[8], h2[8];
        #pragma unroll
        for (int j = 0; j < 8; ++j) {
            float z = bm1[j];
            #pragma unroll
            for (int i = 0; i < 8; ++i) z += Wm1[j*8 + i] * in[i];
            h1[j] = fast_elu(z);
        }
        #pragma unroll
        for (int j = 0; j < 8; ++j) {
            float z = bm2[j];
            #pragma unroll
            for (int i = 0; i < 8; ++i) z += Wm2[j*8 + i] * h1[i];
            h2[j] = fast_elu(z);
        }
        #pragma unroll
        for (int o = 0; o < 4; ++o) {
            float z = bm3[o];
            #pragma unroll
            for (int j = 0; j < 8; ++j) z += Wm3[o*8 + j] * h2[j];
            mlpout[(size_t)o * N_EDGES + eid] = z;
        }
    }
}

// ---------------------------------------------------------------- launch
extern "C" void kernel_launch(void* const* d_in, const int* in_sizes, int n_in,
                              void* d_out, int out_size, void* d_ws, size_t ws_size,
                              hipStream_t stream) {
    const float* x    = (const float*)d_in[0];
    const int*   ei   = (const int*)  d_in[1];
    const float* adj  = (const float*)d_in[2];
    const float* Wq   = (const float*)d_in[4];
    const float* bq   = (const float*)d_in[5];
    const float* Wk   = (const float*)d_in[6];
    const float* bk   = (const float*)d_in[7];
    const float* Wv   = (const float*)d_in[8];
    const float* bv   = (const float*)d_in[9];
    const float* We   = (const float*)d_in[10];
    const float* Wsk  = (const float*)d_in[11];
    const float* bsk  = (const float*)d_in[12];
    const float* Wmc1 = (const float*)d_in[13];
    const float* bmc1 = (const float*)d_in[14];
    const float* Wmc2 = (const float*)d_in[15];
    const float* bmc2 = (const float*)d_in[16];
    const float* Wm1  = (const float*)d_in[17];
    const float* bm1  = (const float*)d_in[18];
    const float* Wm2  = (const float*)d_in[19];
    const float* bm2  = (const float*)d_in[20];
    const float* Wm3  = (const float*)d_in[21];
    const float* bm3  = (const float*)d_in[22];

    // ---- workspace layout (~90 MB total)
    char* w = (char*)d_ws;
    unsigned short* xb   = (unsigned short*)w; w += (size_t)N_NODES * DIM * 2;        // 5.12 MB
    unsigned short* WALL = (unsigned short*)w; w += (size_t)4096 * DIM * 2;           // 2.10 MB
    float*          BALL = (float*)w;          w += (size_t)4096 * 4;                 // 16 KB
    unsigned short* QKVS = (unsigned short*)w; w += (size_t)N_NODES * NCH * 4 * DIM * 2; // 81.92 MB
    int* degi    = (int*)w; w += N_NODES * 4;
    int* rowptr  = (int*)w; w += (N_NODES + 1) * 4;
    int* cursor  = (int*)w; w += N_NODES * 4;
    int* csr_eid = (int*)w; w += N_EDGES * 4;
    int* csr_src = (int*)w; w += N_EDGES * 4;

    float* xout   = (float*)d_out;
    float* mlpout = xout + (size_t)N_NODES * DIM;

    // ---- fused prep (cvt x + pack W + degree) ; degi must be zeroed first
    hipMemsetAsync(degi, 0, N_NODES * sizeof(int), stream);
    prep<<<PREP_CVT_BLKS + PREP_PACK_BLKS + PREP_DEG_BLKS, 256, 0, stream>>>(
        x, Wq, Wk, Wv, Wsk, bq, bk, bv, bsk, ei, xb, WALL, BALL, degi);

    // ---- prefix sum
    scan_kernel<<<1, 1024, 0, stream>>>(degi, rowptr, cursor);

    // ---- GEMM (BK=64, 128x128, f16 MFMA) + CSR scatter in one launch
    gemm_scatter<<<NWG + SCAT_BLKS, 256, 0, stream>>>(xb, WALL, BALL, QKVS,
                                                      ei, cursor, csr_eid, csr_src);

    // ---- fused edge pass + node MLP + edge MLP: writes both outputs directly
    edge_fused<<<N_NODES, 256, 0, stream>>>(rowptr, csr_eid, csr_src, adj, We,
                                            QKVS, Wmc1, bmc1, Wmc2, bmc2,
                                            Wm1, bm1, Wm2, bm2, Wm3, bm3,
                                            xout, mlpout);
}